// Round 4
// baseline (120.388 us; speedup 1.0000x reference)
//
#include <hip/hip_runtime.h>
#include <hip/hip_bf16.h>
#include <string.h>

typedef __attribute__((ext_vector_type(8))) short short8;
typedef __attribute__((ext_vector_type(4))) float f32x4;
typedef __attribute__((ext_vector_type(4))) int int4v;
typedef __attribute__((ext_vector_type(4))) float float4v;
typedef __attribute__((ext_vector_type(4))) unsigned short ushort4v;

#define LOG2E 1.44269504088896340736f
#define NB 8
#define NN 2048
#define NF 128
#define NWAVES 8
#define JW (NN / NWAVES)          /* 256 j per wave */
#define PKW (NN / 64)             /* 32 u64 words per row */
#define PKWORDS (NB * NN * PKW)   /* 524288 */

static __device__ inline unsigned short f2bf(float x) {
    __hip_bfloat16 b = __float2bfloat16(x);
    unsigned short u;
    __builtin_memcpy(&u, &b, 2);
    return u;
}
static __device__ inline float bf2f(unsigned short u) {
    union { unsigned u; float f; } v;
    v.u = ((unsigned)u) << 16;
    return v.f;
}

// ---------------- k_sniff: detect input dtype (1 = bf16, 0 = f32) ----------
__global__ void k_sniff(const unsigned short* __restrict__ hraw,
                        int* __restrict__ flag) {
    int lane = threadIdx.x;
    int cnt = 0;
    for (int i = lane; i < 512; i += 64) {
        int e = (hraw[i] >> 7) & 0xFF;
        cnt += (e >= 102 && e <= 139) ? 1 : 0;
    }
#pragma unroll
    for (int off = 1; off < 64; off <<= 1) cnt += __shfl_xor(cnt, off);
    if (lane == 0) *flag = (cnt >= 450) ? 1 : 0;
}

// ---------------- k_pack: bit-pack adj (coalesced stream, ballot) ----------
// pk[(b*NN+row)*PKW + w] bit i = (adj[b][row][w*64+i] > 0)
__global__ __launch_bounds__(256) void k_pack(const int* __restrict__ adj,
                                              unsigned long long* __restrict__ pk) {
    const int wid = blockIdx.x * 4 + (threadIdx.x >> 6);   // 0..4095
    const int lane = threadIdx.x & 63;
    const int wpw = PKWORDS / 4096;                        // 128 words/wave
    const size_t w0 = (size_t)wid * wpw;
    for (int i = 0; i < wpw; i += 4) {
        int v0 = adj[((w0 + i) << 6) | lane];
        int v1 = adj[((w0 + i + 1) << 6) | lane];
        int v2 = adj[((w0 + i + 2) << 6) | lane];
        int v3 = adj[((w0 + i + 3) << 6) | lane];
        unsigned long long m0 = __ballot(v0 > 0);
        unsigned long long m1 = __ballot(v1 > 0);
        unsigned long long m2 = __ballot(v2 > 0);
        unsigned long long m3 = __ballot(v3 > 0);
        if (lane == 0) {
            pk[w0 + i] = m0;
            pk[w0 + i + 1] = m1;
            pk[w0 + i + 2] = m2;
            pk[w0 + i + 3] = m3;
        }
    }
}

// ---------------- k_prep: WT hi/lo split-transpose + scaled a vectors ------
__global__ __launch_bounds__(256) void k_prep(const void* __restrict__ Wraw,
                                              const void* __restrict__ araw,
                                              const int* __restrict__ flag,
                                              short* __restrict__ WThi,
                                              short* __restrict__ WTlo,
                                              float* __restrict__ a1s,
                                              float* __restrict__ a2s) {
    const int bf16w = *flag;
    int idx = blockIdx.x * 256 + threadIdx.x;   // 0..16383
    int k = idx >> 7, n = idx & 127;
    float x = bf16w ? bf2f(((const unsigned short*)Wraw)[idx])
                    : ((const float*)Wraw)[idx];
    unsigned short hi = f2bf(x);
    float lo = x - bf2f(hi);
    WThi[n * 128 + k] = (short)hi;
    WTlo[n * 128 + k] = (short)f2bf(lo);
    if (blockIdx.x == 0) {
        int i = threadIdx.x;                    // 0..255
        float av = bf16w ? bf2f(((const unsigned short*)araw)[i])
                         : ((const float*)araw)[i];
        if (i < 128) a1s[i] = LOG2E * av;
        else a2s[i - 128] = LOG2E * av;
    }
}

// ---------------- k_gemm: Wh (hi/lo split MFMA, f32-accurate) --------------
__global__ __launch_bounds__(64) void k_gemm(const void* __restrict__ hraw,
                                             const int* __restrict__ flag,
                                             const short* __restrict__ WThi,
                                             const short* __restrict__ WTlo,
                                             const float* __restrict__ a1s,
                                             const float* __restrict__ a2s,
                                             float* __restrict__ s1,
                                             float* __restrict__ s2,
                                             short* __restrict__ WhT) {
    const int lane = threadIdx.x;
    const int lo = lane & 15, g = lane >> 4;
    const int i0 = blockIdx.x * 16;            // global row base over B*N
    const int bf16w = *flag;

    short8 ahi[4], alo[4];
    if (bf16w) {
        const short* h16 = (const short*)hraw;
#pragma unroll
        for (int kc = 0; kc < 4; ++kc) {
            ahi[kc] = *(const short8*)(h16 + (size_t)(i0 + lo) * NF + kc * 32 + g * 8);
            alo[kc] = (short8){0, 0, 0, 0, 0, 0, 0, 0};
        }
    } else {
        const float* hf = (const float*)hraw;
#pragma unroll
        for (int kc = 0; kc < 4; ++kc) {
            const float* p = hf + (size_t)(i0 + lo) * NF + kc * 32 + g * 8;
            float4v x0 = *(const float4v*)(p);
            float4v x1 = *(const float4v*)(p + 4);
            short8 h8, l8;
#pragma unroll
            for (int q = 0; q < 4; ++q) {
                unsigned short u0 = f2bf(x0[q]);
                h8[q] = (short)u0;
                l8[q] = (short)f2bf(x0[q] - bf2f(u0));
                unsigned short u1 = f2bf(x1[q]);
                h8[q + 4] = (short)u1;
                l8[q + 4] = (short)f2bf(x1[q] - bf2f(u1));
            }
            ahi[kc] = h8;
            alo[kc] = l8;
        }
    }

    f32x4 acc[8];
#pragma unroll
    for (int t = 0; t < 8; ++t) acc[t] = (f32x4){0.f, 0.f, 0.f, 0.f};

#pragma unroll
    for (int t = 0; t < 8; ++t) {
#pragma unroll
        for (int kc = 0; kc < 4; ++kc) {
            const size_t boff = (size_t)(lo + 16 * t) * NF + kc * 32 + g * 8;
            short8 bhi = *(const short8*)(WThi + boff);
            short8 blo = *(const short8*)(WTlo + boff);
            acc[t] = __builtin_amdgcn_mfma_f32_16x16x32_bf16(ahi[kc], bhi, acc[t], 0, 0, 0);
            acc[t] = __builtin_amdgcn_mfma_f32_16x16x32_bf16(ahi[kc], blo, acc[t], 0, 0, 0);
            acc[t] = __builtin_amdgcn_mfma_f32_16x16x32_bf16(alo[kc], bhi, acc[t], 0, 0, 0);
        }
    }

    const int b = i0 >> 11;
    const int n0 = i0 & 2047;
    short* wt = WhT + (size_t)b * NF * NN;
#pragma unroll
    for (int t = 0; t < 8; ++t) {
        ushort4v u;
#pragma unroll
        for (int r = 0; r < 4; ++r) u[r] = f2bf(acc[t][r]);
        *(ushort4v*)(wt + (size_t)(lo + 16 * t) * NN + n0 + g * 4) = u;
    }

    float a1f[8], a2f[8];
#pragma unroll
    for (int t = 0; t < 8; ++t) {
        a1f[t] = a1s[lo + 16 * t];
        a2f[t] = a2s[lo + 16 * t];
    }
#pragma unroll
    for (int r = 0; r < 4; ++r) {
        float d1 = 0.f, d2 = 0.f;
#pragma unroll
        for (int t = 0; t < 8; ++t) {
            float w = acc[t][r];
            d1 += w * a1f[t];
            d2 += w * a2f[t];
        }
#pragma unroll
        for (int off = 1; off < 16; off <<= 1) {
            d1 += __shfl_xor(d1, off);
            d2 += __shfl_xor(d2, off);
        }
        if (lo == 0) {
            s1[i0 + g * 4 + r] = d1;
            s2[i0 + g * 4 + r] = d2;
        }
    }
}

// ---------------- k_s2max: per-batch max of s2 ------------------------------
__global__ __launch_bounds__(256) void k_s2max(const float* __restrict__ s2,
                                               float* __restrict__ s2m) {
    int b = blockIdx.x;
    float m = -1e30f;
    for (int i = threadIdx.x; i < NN; i += 256) m = fmaxf(m, s2[b * NN + i]);
#pragma unroll
    for (int off = 1; off < 64; off <<= 1) m = fmaxf(m, __shfl_xor(m, off));
    __shared__ float sm[4];
    if ((threadIdx.x & 63) == 0) sm[threadIdx.x >> 6] = m;
    __syncthreads();
    if (threadIdx.x == 0)
        s2m[b] = fmaxf(fmaxf(sm[0], sm[1]), fmaxf(sm[2], sm[3]));
}

// ---------------- k_attn2: fused masked softmax + PV (packed adj) ----------
__global__ __launch_bounds__(512, 4) void k_attn2(const unsigned long long* __restrict__ pk,
                                                  const float* __restrict__ s1,
                                                  const float* __restrict__ s2,
                                                  const float* __restrict__ s2m,
                                                  const short* __restrict__ WhT,
                                                  const int* __restrict__ flag,
                                                  void* __restrict__ out) {
    const int tid = threadIdx.x;
    const int lane = tid & 63;
    const int wid = tid >> 6;                  // 0..7
    const int lo = lane & 15, g = lane >> 4;
    const int gid = blockIdx.x;                // 0..1023
    const int rg = gid & 127;
    const int b = gid >> 7;

    __shared__ float ob[16 * 132];
    __shared__ float ls[16];

    const int row = rg * 16 + lo;              // this lane's P-row (A-frag m)
    const float s1v = s1[b * NN + row];
    const float tm = s1v + s2m[b];
    const float M = fmaxf(tm, 0.2f * tm);      // LeakyReLU upper bound, scaled
    const unsigned long long* pkb = pk + (size_t)(b * NN + row) * PKW;
    const float* s2p = s2 + b * NN;
    const short* vb = WhT + (size_t)b * NF * NN;

    const int jbeg = wid * JW;
    const int jend = jbeg + JW;

    f32x4 acc[8];
#pragma unroll
    for (int t = 0; t < 8; ++t) acc[t] = (f32x4){0.f, 0.f, 0.f, 0.f};
    float lsum = 0.f;

    for (int j0 = jbeg; j0 < jend; j0 += 64) {
        const unsigned long long m = pkb[j0 >> 6];
        short8 pa[2];
#pragma unroll
        for (int c = 0; c < 2; ++c) {
            const int off = j0 + c * 32 + g * 8;
            const unsigned bits = (unsigned)(m >> (c * 32 + g * 8)) & 0xFFu;
            float4v z0 = *(const float4v*)(s2p + off);
            float4v z1 = *(const float4v*)(s2p + off + 4);
            float p[8];
#pragma unroll
            for (int q = 0; q < 4; ++q) {
                float t0 = s1v + z0[q];
                float e0 = fmaxf(t0, 0.2f * t0);
                p[q] = ((bits >> q) & 1u) ? exp2f(e0 - M) : 0.f;
                float t1 = s1v + z1[q];
                float e1 = fmaxf(t1, 0.2f * t1);
                p[q + 4] = ((bits >> (q + 4)) & 1u) ? exp2f(e1 - M) : 0.f;
            }
            short8 s;
#pragma unroll
            for (int q = 0; q < 8; ++q) {
                unsigned short u = f2bf(p[q]);
                s[q] = (short)u;
                lsum += bf2f(u);               // consistent with MFMA numerator
            }
            pa[c] = s;
        }
#pragma unroll
        for (int t = 0; t < 8; ++t) {
            const short* vp = vb + (size_t)(lo + 16 * t) * NN + j0 + g * 8;
            short8 v0 = *(const short8*)(vp);
            short8 v1 = *(const short8*)(vp + 32);
            acc[t] = __builtin_amdgcn_mfma_f32_16x16x32_bf16(pa[0], v0, acc[t], 0, 0, 0);
            acc[t] = __builtin_amdgcn_mfma_f32_16x16x32_bf16(pa[1], v1, acc[t], 0, 0, 0);
        }
    }

    lsum += __shfl_xor(lsum, 16);
    lsum += __shfl_xor(lsum, 32);

    // ---- deterministic serialized LDS combine across the 8 waves ----
    for (int w = 0; w < NWAVES; ++w) {
        if (wid == w) {
            if (w == 0) {
#pragma unroll
                for (int t = 0; t < 8; ++t)
#pragma unroll
                    for (int r = 0; r < 4; ++r)
                        ob[(g * 4 + r) * 132 + lo + 16 * t] = acc[t][r];
                if (g == 0) ls[lo] = lsum;
            } else {
#pragma unroll
                for (int t = 0; t < 8; ++t)
#pragma unroll
                    for (int r = 0; r < 4; ++r)
                        ob[(g * 4 + r) * 132 + lo + 16 * t] += acc[t][r];
                if (g == 0) ls[lo] += lsum;
            }
        }
        __syncthreads();
    }

    // ---- final: divide, ELU, store ----
    const int bf16w = *flag;
    const int rr = tid >> 5;                   // 0..15
    const int c0 = (tid & 31) * 4;             // 0..124
    const float inv = 1.0f / ls[rr];
    const size_t obase = ((size_t)b * NN + rg * 16 + rr) * NF + c0;
    float y[4];
#pragma unroll
    for (int q = 0; q < 4; ++q) {
        float x = ob[rr * 132 + c0 + q] * inv;
        y[q] = (x > 0.f) ? x : (exp2f(x * LOG2E) - 1.0f);
    }
    if (bf16w) {
        ushort4v u;
#pragma unroll
        for (int q = 0; q < 4; ++q) u[q] = f2bf(y[q]);
        *(ushort4v*)((__hip_bfloat16*)out + obase) = u;
    } else {
        float4v v;
#pragma unroll
        for (int q = 0; q < 4; ++q) v[q] = y[q];
        *(float4v*)((float*)out + obase) = v;
    }
}

extern "C" void kernel_launch(void* const* d_in, const int* in_sizes, int n_in,
                              void* d_out, int out_size, void* d_ws, size_t ws_size,
                              hipStream_t stream) {
    const void* h = d_in[0];                    // f32 or bf16 [8][2048][128]
    const int* adj = (const int*)d_in[1];       // int32 [8][2048][2048]
    const void* W = d_in[2];                    // f32 or bf16 [128][128]
    const void* a = d_in[3];                    // f32 or bf16 [256]

    char* ws = (char*)d_ws;
    auto align256 = [](size_t x) { return (x + 255) & ~(size_t)255; };
    size_t off = 0;
    int* flag = (int*)(ws + off);     off = align256(off + 256);
    short* WThi = (short*)(ws + off); off = align256(off + (size_t)128 * 128 * 2);
    short* WTlo = (short*)(ws + off); off = align256(off + (size_t)128 * 128 * 2);
    float* a1s = (float*)(ws + off);  off = align256(off + 128 * 4);
    float* a2s = (float*)(ws + off);  off = align256(off + 128 * 4);
    short* WhT = (short*)(ws + off);  off = align256(off + (size_t)NB * NF * NN * 2);
    float* s1 = (float*)(ws + off);   off = align256(off + (size_t)NB * NN * 4);
    float* s2 = (float*)(ws + off);   off = align256(off + (size_t)NB * NN * 4);
    float* s2m = (float*)(ws + off);  off = align256(off + (size_t)NB * 4);
    unsigned long long* pk = (unsigned long long*)(ws + off);
    off = align256(off + (size_t)PKWORDS * 8);

    k_sniff<<<1, 64, 0, stream>>>((const unsigned short*)h, flag);
    k_pack<<<1024, 256, 0, stream>>>(adj, pk);
    k_prep<<<64, 256, 0, stream>>>(W, a, flag, WThi, WTlo, a1s, a2s);
    k_gemm<<<NB * NN / 16, 64, 0, stream>>>(h, flag, WThi, WTlo, a1s, a2s, s1, s2, WhT);
    k_s2max<<<NB, 256, 0, stream>>>(s2, s2m);
    k_attn2<<<NB * NN / 16, 512, 0, stream>>>(pk, s1, s2, s2m, WhT, flag, d_out);
}

// Round 5
// 99.014 us; speedup vs baseline: 1.2159x; 1.2159x over previous
//
#include <hip/hip_runtime.h>
#include <hip/hip_bf16.h>
#include <string.h>

typedef __attribute__((ext_vector_type(8))) short short8;
typedef __attribute__((ext_vector_type(4))) float f32x4;
typedef __attribute__((ext_vector_type(4))) int int4v;
typedef __attribute__((ext_vector_type(4))) float float4v;
typedef __attribute__((ext_vector_type(4))) unsigned short ushort4v;

#define LOG2E 1.44269504088896340736f
#define NB 8
#define NN 2048
#define NF 128
#define PKW (NN / 64)             /* 32 u64 words per row */
#define PKWORDS (NB * NN * PKW)   /* 524288 */

static __device__ inline unsigned short f2bf(float x) {
    __hip_bfloat16 b = __float2bfloat16(x);
    unsigned short u;
    __builtin_memcpy(&u, &b, 2);
    return u;
}
static __device__ inline float bf2f(unsigned short u) {
    union { unsigned u; float f; } v;
    v.u = ((unsigned)u) << 16;
    return v.f;
}

// ---------------- k_sniff: detect input dtype (1 = bf16, 0 = f32) ----------
__global__ void k_sniff(const unsigned short* __restrict__ hraw,
                        int* __restrict__ flag) {
    int lane = threadIdx.x;
    int cnt = 0;
    for (int i = lane; i < 512; i += 64) {
        int e = (hraw[i] >> 7) & 0xFF;
        cnt += (e >= 102 && e <= 139) ? 1 : 0;
    }
#pragma unroll
    for (int off = 1; off < 64; off <<= 1) cnt += __shfl_xor(cnt, off);
    if (lane == 0) *flag = (cnt >= 450) ? 1 : 0;
}

// ---------------- k_pack: bit-pack adj (coalesced stream, ballot) ----------
__global__ __launch_bounds__(256) void k_pack(const int* __restrict__ adj,
                                              unsigned long long* __restrict__ pk) {
    const int wid = blockIdx.x * 4 + (threadIdx.x >> 6);   // 0..4095
    const int lane = threadIdx.x & 63;
    const int wpw = PKWORDS / 4096;                        // 128 words/wave
    const size_t w0 = (size_t)wid * wpw;
    for (int i = 0; i < wpw; i += 4) {
        int v0 = adj[((w0 + i) << 6) | lane];
        int v1 = adj[((w0 + i + 1) << 6) | lane];
        int v2 = adj[((w0 + i + 2) << 6) | lane];
        int v3 = adj[((w0 + i + 3) << 6) | lane];
        unsigned long long m0 = __ballot(v0 > 0);
        unsigned long long m1 = __ballot(v1 > 0);
        unsigned long long m2 = __ballot(v2 > 0);
        unsigned long long m3 = __ballot(v3 > 0);
        if (lane == 0) {
            pk[w0 + i] = m0;
            pk[w0 + i + 1] = m1;
            pk[w0 + i + 2] = m2;
            pk[w0 + i + 3] = m3;
        }
    }
}

// ---------------- k_prep: WT hi/lo split-transpose + scaled a vectors ------
__global__ __launch_bounds__(256) void k_prep(const void* __restrict__ Wraw,
                                              const void* __restrict__ araw,
                                              const int* __restrict__ flag,
                                              short* __restrict__ WThi,
                                              short* __restrict__ WTlo,
                                              float* __restrict__ a1s,
                                              float* __restrict__ a2s) {
    const int bf16w = *flag;
    int idx = blockIdx.x * 256 + threadIdx.x;   // 0..16383
    int k = idx >> 7, n = idx & 127;
    float x = bf16w ? bf2f(((const unsigned short*)Wraw)[idx])
                    : ((const float*)Wraw)[idx];
    unsigned short hi = f2bf(x);
    float lo = x - bf2f(hi);
    WThi[n * 128 + k] = (short)hi;
    WTlo[n * 128 + k] = (short)f2bf(lo);
    if (blockIdx.x == 0) {
        int i = threadIdx.x;                    // 0..255
        float av = bf16w ? bf2f(((const unsigned short*)araw)[i])
                         : ((const float*)araw)[i];
        if (i < 128) a1s[i] = LOG2E * av;
        else a2s[i - 128] = LOG2E * av;
    }
}

// ---------------- k_gemm: Wh (hi/lo split MFMA, f32-accurate) --------------
__global__ __launch_bounds__(64) void k_gemm(const void* __restrict__ hraw,
                                             const int* __restrict__ flag,
                                             const short* __restrict__ WThi,
                                             const short* __restrict__ WTlo,
                                             const float* __restrict__ a1s,
                                             const float* __restrict__ a2s,
                                             float* __restrict__ s1,
                                             float* __restrict__ s2,
                                             short* __restrict__ WhT) {
    const int lane = threadIdx.x;
    const int lo = lane & 15, g = lane >> 4;
    const int i0 = blockIdx.x * 16;            // global row base over B*N
    const int bf16w = *flag;

    short8 ahi[4], alo[4];
    if (bf16w) {
        const short* h16 = (const short*)hraw;
#pragma unroll
        for (int kc = 0; kc < 4; ++kc) {
            ahi[kc] = *(const short8*)(h16 + (size_t)(i0 + lo) * NF + kc * 32 + g * 8);
            alo[kc] = (short8){0, 0, 0, 0, 0, 0, 0, 0};
        }
    } else {
        const float* hf = (const float*)hraw;
#pragma unroll
        for (int kc = 0; kc < 4; ++kc) {
            const float* p = hf + (size_t)(i0 + lo) * NF + kc * 32 + g * 8;
            float4v x0 = *(const float4v*)(p);
            float4v x1 = *(const float4v*)(p + 4);
            short8 h8, l8;
#pragma unroll
            for (int q = 0; q < 4; ++q) {
                unsigned short u0 = f2bf(x0[q]);
                h8[q] = (short)u0;
                l8[q] = (short)f2bf(x0[q] - bf2f(u0));
                unsigned short u1 = f2bf(x1[q]);
                h8[q + 4] = (short)u1;
                l8[q + 4] = (short)f2bf(x1[q] - bf2f(u1));
            }
            ahi[kc] = h8;
            alo[kc] = l8;
        }
    }

    f32x4 acc[8];
#pragma unroll
    for (int t = 0; t < 8; ++t) acc[t] = (f32x4){0.f, 0.f, 0.f, 0.f};

#pragma unroll
    for (int t = 0; t < 8; ++t) {
#pragma unroll
        for (int kc = 0; kc < 4; ++kc) {
            const size_t boff = (size_t)(lo + 16 * t) * NF + kc * 32 + g * 8;
            short8 bhi = *(const short8*)(WThi + boff);
            short8 blo = *(const short8*)(WTlo + boff);
            acc[t] = __builtin_amdgcn_mfma_f32_16x16x32_bf16(ahi[kc], bhi, acc[t], 0, 0, 0);
            acc[t] = __builtin_amdgcn_mfma_f32_16x16x32_bf16(ahi[kc], blo, acc[t], 0, 0, 0);
            acc[t] = __builtin_amdgcn_mfma_f32_16x16x32_bf16(alo[kc], bhi, acc[t], 0, 0, 0);
        }
    }

    const int b = i0 >> 11;
    const int n0 = i0 & 2047;
    short* wt = WhT + (size_t)b * NF * NN;
#pragma unroll
    for (int t = 0; t < 8; ++t) {
        ushort4v u;
#pragma unroll
        for (int r = 0; r < 4; ++r) u[r] = f2bf(acc[t][r]);
        *(ushort4v*)(wt + (size_t)(lo + 16 * t) * NN + n0 + g * 4) = u;
    }

    float a1f[8], a2f[8];
#pragma unroll
    for (int t = 0; t < 8; ++t) {
        a1f[t] = a1s[lo + 16 * t];
        a2f[t] = a2s[lo + 16 * t];
    }
#pragma unroll
    for (int r = 0; r < 4; ++r) {
        float d1 = 0.f, d2 = 0.f;
#pragma unroll
        for (int t = 0; t < 8; ++t) {
            float w = acc[t][r];
            d1 += w * a1f[t];
            d2 += w * a2f[t];
        }
#pragma unroll
        for (int off = 1; off < 16; off <<= 1) {
            d1 += __shfl_xor(d1, off);
            d2 += __shfl_xor(d2, off);
        }
        if (lo == 0) {
            s1[i0 + g * 4 + r] = d1;
            s2[i0 + g * 4 + r] = d2;
        }
    }
}

// ---------------- k_s2max: per-batch max of s2 ------------------------------
__global__ __launch_bounds__(256) void k_s2max(const float* __restrict__ s2,
                                               float* __restrict__ s2m) {
    int b = blockIdx.x;
    float m = -1e30f;
    for (int i = threadIdx.x; i < NN; i += 256) m = fmaxf(m, s2[b * NN + i]);
#pragma unroll
    for (int off = 1; off < 64; off <<= 1) m = fmaxf(m, __shfl_xor(m, off));
    __shared__ float sm[4];
    if ((threadIdx.x & 63) == 0) sm[threadIdx.x >> 6] = m;
    __syncthreads();
    if (threadIdx.x == 0)
        s2m[b] = fmaxf(fmaxf(sm[0], sm[1]), fmaxf(sm[2], sm[3]));
}

// ---------------- k_attn3: LDS-staged fused masked softmax + PV -------------
// block = 256 thr = 4 waves = 4 row-groups (64 rows), one j-range (NN/JS).
// Per 64-j tile: block stages WhT[128][64] into LDS (XOR-swizzled, double-
// buffered, loads issued one tile ahead); waves read B-frags from LDS.
template <int FINAL, int JS>
__global__ __launch_bounds__(256, 2) void k_attn3(const unsigned long long* __restrict__ pk,
                                                  const float* __restrict__ s1,
                                                  const float* __restrict__ s2,
                                                  const float* __restrict__ s2m,
                                                  const short* __restrict__ WhT,
                                                  const int* __restrict__ flag,
                                                  void* __restrict__ out,
                                                  float* __restrict__ pO,
                                                  float* __restrict__ pL) {
    const int tid = threadIdx.x;
    const int lane = tid & 63, wid = tid >> 6;
    const int lo = lane & 15, g = lane >> 4;
    int gid = blockIdx.x;
    const int js = (JS > 1) ? (gid % JS) : 0;
    gid /= JS;
    const int blk = gid & 31;                  // 64-row chunk within batch
    const int b = gid >> 5;
    const int rowbase = blk * 64 + wid * 16;   // wave's 16-row group
    const int row = rowbase + lo;
    const int jbeg = js * (NN / JS);
    const int NT = (NN / JS) / 64;

    __shared__ short lds[2][128 * 64];

    const float s1v = s1[b * NN + row];
    const float tm = s1v + s2m[b];
    const float M = fmaxf(tm, 0.2f * tm);
    const unsigned long long* pkr = pk + (size_t)(b * NN + row) * PKW + (jbeg >> 6);
    const float* s2p = s2 + b * NN + jbeg;
    const short* vb = WhT + (size_t)b * NF * NN;

    // staging role: thread -> (feature, 64B half of the 128B j-row)
    const int sf = tid >> 1;
    const int sh = tid & 1;
    const short* sbase = vb + (size_t)sf * NN + jbeg + sh * 32;
    char* ldsc0 = (char*)&lds[0][0];
    char* ldsc1 = (char*)&lds[1][0];
    const unsigned swz = (unsigned)((sf & 7) << 4);
    const unsigned wb0 = (unsigned)(sf * 128 + sh * 64);
    const unsigned rsw = (unsigned)((lo & 7) << 4);

    f32x4 acc[8];
#pragma unroll
    for (int t = 0; t < 8; ++t) acc[t] = (f32x4){0.f, 0.f, 0.f, 0.f};
    float lsum = 0.f;

    // prologue: stage tile 0
    {
        short8 s0 = *(const short8*)(sbase);
        short8 s1r = *(const short8*)(sbase + 8);
        short8 s2r = *(const short8*)(sbase + 16);
        short8 s3r = *(const short8*)(sbase + 24);
        *(short8*)(ldsc0 + ((wb0 + 0) ^ swz)) = s0;
        *(short8*)(ldsc0 + ((wb0 + 16) ^ swz)) = s1r;
        *(short8*)(ldsc0 + ((wb0 + 32) ^ swz)) = s2r;
        *(short8*)(ldsc0 + ((wb0 + 48) ^ swz)) = s3r;
    }
    unsigned long long mcur = pkr[0];
    __syncthreads();

    int cur = 0;
    for (int t = 0; t < NT; ++t) {
        // ---- issue next tile's staging loads early (hide under compute) ----
        short8 sn0, sn1, sn2, sn3;
        unsigned long long mnext = 0;
        const bool more = (t + 1 < NT);
        if (more) {
            const short* sp = sbase + (t + 1) * 64;
            sn0 = *(const short8*)(sp);
            sn1 = *(const short8*)(sp + 8);
            sn2 = *(const short8*)(sp + 16);
            sn3 = *(const short8*)(sp + 24);
            mnext = pkr[t + 1];
        }
        const char* cb = cur ? ldsc1 : ldsc0;

        // ---- P for this wave's 16 rows x 64 j ----
        const float* zp = s2p + t * 64 + g * 8;
        float4v z00 = *(const float4v*)(zp);
        float4v z01 = *(const float4v*)(zp + 4);
        float4v z10 = *(const float4v*)(zp + 32);
        float4v z11 = *(const float4v*)(zp + 36);
        const unsigned bits0 = (unsigned)(mcur >> (g * 8)) & 0xFFu;
        const unsigned bits1 = (unsigned)(mcur >> (32 + g * 8)) & 0xFFu;
        short8 pa0, pa1;
#pragma unroll
        for (int q = 0; q < 4; ++q) {
            float t0 = s1v + z00[q];
            float e0 = fmaxf(t0, 0.2f * t0);
            float p0 = ((bits0 >> q) & 1u) ? exp2f(e0 - M) : 0.f;
            float t1 = s1v + z01[q];
            float e1 = fmaxf(t1, 0.2f * t1);
            float p1 = ((bits0 >> (q + 4)) & 1u) ? exp2f(e1 - M) : 0.f;
            float t2 = s1v + z10[q];
            float e2 = fmaxf(t2, 0.2f * t2);
            float p2 = ((bits1 >> q) & 1u) ? exp2f(e2 - M) : 0.f;
            float t3 = s1v + z11[q];
            float e3 = fmaxf(t3, 0.2f * t3);
            float p3 = ((bits1 >> (q + 4)) & 1u) ? exp2f(e3 - M) : 0.f;
            unsigned short u0 = f2bf(p0), u1 = f2bf(p1), u2 = f2bf(p2), u3 = f2bf(p3);
            pa0[q] = (short)u0; pa0[q + 4] = (short)u1;
            pa1[q] = (short)u2; pa1[q + 4] = (short)u3;
            lsum += bf2f(u0) + bf2f(u1) + bf2f(u2) + bf2f(u3);
        }

        // ---- 16 MFMAs, B-frags from swizzled LDS ----
#pragma unroll
        for (int t8 = 0; t8 < 8; ++t8) {
            const unsigned rb0 = ((unsigned)((lo + 16 * t8) * 128 + g * 16)) ^ rsw;
            const unsigned rb1 = ((unsigned)((lo + 16 * t8) * 128 + 64 + g * 16)) ^ rsw;
            short8 v0 = *(const short8*)(cb + rb0);
            short8 v1 = *(const short8*)(cb + rb1);
            acc[t8] = __builtin_amdgcn_mfma_f32_16x16x32_bf16(pa0, v0, acc[t8], 0, 0, 0);
            acc[t8] = __builtin_amdgcn_mfma_f32_16x16x32_bf16(pa1, v1, acc[t8], 0, 0, 0);
        }

        // ---- write staged regs into the other buffer ----
        if (more) {
            char* wb = cur ? ldsc0 : ldsc1;
            *(short8*)(wb + ((wb0 + 0) ^ swz)) = sn0;
            *(short8*)(wb + ((wb0 + 16) ^ swz)) = sn1;
            *(short8*)(wb + ((wb0 + 32) ^ swz)) = sn2;
            *(short8*)(wb + ((wb0 + 48) ^ swz)) = sn3;
            mcur = mnext;
        }
        __syncthreads();
        cur ^= 1;
    }

    // row-sum for row `lo` across the 4 k-slices
    lsum += __shfl_xor(lsum, 16);
    lsum += __shfl_xor(lsum, 32);

    if (FINAL) {
        const int bf16w = *flag;
        float inv[4];
#pragma unroll
        for (int r = 0; r < 4; ++r) inv[r] = 1.0f / __shfl(lsum, g * 4 + r);
#pragma unroll
        for (int t8 = 0; t8 < 8; ++t8) {
#pragma unroll
            for (int r = 0; r < 4; ++r) {
                float x = acc[t8][r] * inv[r];
                float y = (x > 0.f) ? x : (exp2f(x * LOG2E) - 1.0f);
                size_t oi = ((size_t)b * NN + rowbase + g * 4 + r) * NF + lo + 16 * t8;
                if (bf16w) ((__hip_bfloat16*)out)[oi] = __float2bfloat16(y);
                else ((float*)out)[oi] = y;
            }
        }
    } else {
        const int grp = b * 128 + blk * 4 + wid;       // 16-row group id
        float* po = pO + (size_t)(grp * JS + js) * (16 * NF);
#pragma unroll
        for (int t8 = 0; t8 < 8; ++t8)
#pragma unroll
            for (int r = 0; r < 4; ++r)
                po[(g * 4 + r) * NF + lo + 16 * t8] = acc[t8][r];
        if (g == 0) pL[(grp * JS + js) * 16 + lo] = lsum;
    }
}

// ---------------- k_combine: merge j-split partials, ELU, store -------------
__global__ __launch_bounds__(256) void k_combine(const float* __restrict__ pO,
                                                 const float* __restrict__ pL,
                                                 const int* __restrict__ flag,
                                                 void* __restrict__ out,
                                                 int jsplit) {
    int idx = blockIdx.x * 256 + threadIdx.x;   // 0 .. B*N*F-1
    if (idx >= NB * NN * NF) return;
    const int bf16w = *flag;
    int col = idx & 127;
    int rowg = idx >> 7;
    int r = rowg & 15;
    int grp = rowg >> 4;          // b*128 + 16-row group
    float o = 0.f, l = 0.f;
    for (int js = 0; js < jsplit; ++js) {
        int task = grp * jsplit + js;
        o += pO[(size_t)task * (16 * NF) + r * NF + col];
        l += pL[task * 16 + r];
    }
    float x = o / l;
    float y = (x > 0.f) ? x : (exp2f(x * LOG2E) - 1.0f);
    if (bf16w) ((__hip_bfloat16*)out)[idx] = __float2bfloat16(y);
    else ((float*)out)[idx] = y;
}

extern "C" void kernel_launch(void* const* d_in, const int* in_sizes, int n_in,
                              void* d_out, int out_size, void* d_ws, size_t ws_size,
                              hipStream_t stream) {
    const void* h = d_in[0];                    // f32 or bf16 [8][2048][128]
    const int* adj = (const int*)d_in[1];       // int32 [8][2048][2048]
    const void* W = d_in[2];                    // f32 or bf16 [128][128]
    const void* a = d_in[3];                    // f32 or bf16 [256]

    char* ws = (char*)d_ws;
    auto align256 = [](size_t x) { return (x + 255) & ~(size_t)255; };
    size_t off = 0;
    int* flag = (int*)(ws + off);     off = align256(off + 256);
    short* WThi = (short*)(ws + off); off = align256(off + (size_t)128 * 128 * 2);
    short* WTlo = (short*)(ws + off); off = align256(off + (size_t)128 * 128 * 2);
    float* a1s = (float*)(ws + off);  off = align256(off + 128 * 4);
    float* a2s = (float*)(ws + off);  off = align256(off + 128 * 4);
    short* WhT = (short*)(ws + off);  off = align256(off + (size_t)NB * NF * NN * 2);
    float* s1 = (float*)(ws + off);   off = align256(off + (size_t)NB * NN * 4);
    float* s2 = (float*)(ws + off);   off = align256(off + (size_t)NB * NN * 4);
    float* s2m = (float*)(ws + off);  off = align256(off + (size_t)NB * 4);
    unsigned long long* pk = (unsigned long long*)(ws + off);
    off = align256(off + (size_t)PKWORDS * 8);

    const int ngrp = NB * 128;                   // 16-row groups
    size_t pO_bytes = (size_t)ngrp * 2 * 16 * NF * 4;
    size_t pL_bytes = (size_t)ngrp * 2 * 16 * 4;
    size_t needSplit = off + pO_bytes + 512 + pL_bytes;
    int jsplit = (ws_size >= needSplit) ? 2 : 1;
    float* pO = nullptr;
    float* pL = nullptr;
    if (jsplit == 2) {
        pO = (float*)(ws + off); off = align256(off + pO_bytes);
        pL = (float*)(ws + off); off = align256(off + pL_bytes);
    }

    k_sniff<<<1, 64, 0, stream>>>((const unsigned short*)h, flag);
    k_pack<<<1024, 256, 0, stream>>>(adj, pk);
    k_prep<<<64, 256, 0, stream>>>(W, a, flag, WThi, WTlo, a1s, a2s);
    k_gemm<<<NB * NN / 16, 64, 0, stream>>>(h, flag, WThi, WTlo, a1s, a2s, s1, s2, WhT);
    k_s2max<<<NB, 256, 0, stream>>>(s2, s2m);
    if (jsplit == 2) {
        k_attn3<0, 2><<<NB * 32 * 2, 256, 0, stream>>>(pk, s1, s2, s2m, WhT, flag,
                                                       d_out, pO, pL);
        int nout = NB * NN * NF;
        k_combine<<<(nout + 255) / 256, 256, 0, stream>>>(pO, pL, flag, d_out, 2);
    } else {
        k_attn3<1, 1><<<NB * 32, 256, 0, stream>>>(pk, s1, s2, s2m, WhT, flag,
                                                   d_out, nullptr, nullptr);
    }
}

// Round 6
// 87.863 us; speedup vs baseline: 1.3702x; 1.1269x over previous
//
#include <hip/hip_runtime.h>
#include <hip/hip_bf16.h>
#include <string.h>

typedef __attribute__((ext_vector_type(8))) short short8;
typedef __attribute__((ext_vector_type(4))) float f32x4;
typedef __attribute__((ext_vector_type(4))) int int4v;
typedef __attribute__((ext_vector_type(4))) float float4v;
typedef __attribute__((ext_vector_type(4))) unsigned short ushort4v;

#define LOG2E 1.44269504088896340736f
#define NB 8
#define NN 2048
#define NF 128
#define PKW (NN / 64)             /* 32 u64 words per row */
#define PKWORDS (NB * NN * PKW)   /* 524288 */

static __device__ inline unsigned short f2bf(float x) {
    __hip_bfloat16 b = __float2bfloat16(x);
    unsigned short u;
    __builtin_memcpy(&u, &b, 2);
    return u;
}
static __device__ inline float bf2f(unsigned short u) {
    union { unsigned u; float f; } v;
    v.u = ((unsigned)u) << 16;
    return v.f;
}

// ---------------- k_sniff: detect input dtype (1 = bf16, 0 = f32) ----------
__global__ void k_sniff(const unsigned short* __restrict__ hraw,
                        int* __restrict__ flag) {
    int lane = threadIdx.x;
    int cnt = 0;
    for (int i = lane; i < 512; i += 64) {
        int e = (hraw[i] >> 7) & 0xFF;
        cnt += (e >= 102 && e <= 139) ? 1 : 0;
    }
#pragma unroll
    for (int off = 1; off < 64; off <<= 1) cnt += __shfl_xor(cnt, off);
    if (lane == 0) *flag = (cnt >= 450) ? 1 : 0;
}

// ---------------- k_pack: bit-pack adj (coalesced stream, ballot) ----------
__global__ __launch_bounds__(256) void k_pack(const int* __restrict__ adj,
                                              unsigned long long* __restrict__ pk) {
    const int wid = blockIdx.x * 4 + (threadIdx.x >> 6);   // 0..4095
    const int lane = threadIdx.x & 63;
    const int wpw = PKWORDS / 4096;                        // 128 words/wave
    const size_t w0 = (size_t)wid * wpw;
    for (int i = 0; i < wpw; i += 4) {
        int v0 = adj[((w0 + i) << 6) | lane];
        int v1 = adj[((w0 + i + 1) << 6) | lane];
        int v2 = adj[((w0 + i + 2) << 6) | lane];
        int v3 = adj[((w0 + i + 3) << 6) | lane];
        unsigned long long m0 = __ballot(v0 > 0);
        unsigned long long m1 = __ballot(v1 > 0);
        unsigned long long m2 = __ballot(v2 > 0);
        unsigned long long m3 = __ballot(v3 > 0);
        if (lane == 0) {
            pk[w0 + i] = m0;
            pk[w0 + i + 1] = m1;
            pk[w0 + i + 2] = m2;
            pk[w0 + i + 3] = m3;
        }
    }
}

// ---------------- k_prep: WT hi/lo split-transpose + scaled a vectors ------
__global__ __launch_bounds__(256) void k_prep(const void* __restrict__ Wraw,
                                              const void* __restrict__ araw,
                                              const int* __restrict__ flag,
                                              short* __restrict__ WThi,
                                              short* __restrict__ WTlo,
                                              float* __restrict__ a1s,
                                              float* __restrict__ a2s) {
    const int bf16w = *flag;
    int idx = blockIdx.x * 256 + threadIdx.x;   // 0..16383
    int k = idx >> 7, n = idx & 127;
    float x = bf16w ? bf2f(((const unsigned short*)Wraw)[idx])
                    : ((const float*)Wraw)[idx];
    unsigned short hi = f2bf(x);
    float lo = x - bf2f(hi);
    WThi[n * 128 + k] = (short)hi;
    WTlo[n * 128 + k] = (short)f2bf(lo);
    if (blockIdx.x == 0) {
        int i = threadIdx.x;                    // 0..255
        float av = bf16w ? bf2f(((const unsigned short*)araw)[i])
                         : ((const float*)araw)[i];
        if (i < 128) a1s[i] = LOG2E * av;
        else a2s[i - 128] = LOG2E * av;
    }
}

// ---------------- k_gemm: Wh (hi/lo split MFMA, f32-accurate) --------------
__global__ __launch_bounds__(64) void k_gemm(const void* __restrict__ hraw,
                                             const int* __restrict__ flag,
                                             const short* __restrict__ WThi,
                                             const short* __restrict__ WTlo,
                                             const float* __restrict__ a1s,
                                             const float* __restrict__ a2s,
                                             float* __restrict__ s1,
                                             float* __restrict__ s2,
                                             short* __restrict__ WhT) {
    const int lane = threadIdx.x;
    const int lo = lane & 15, g = lane >> 4;
    const int i0 = blockIdx.x * 16;            // global row base over B*N
    const int bf16w = *flag;

    short8 ahi[4], alo[4];
    if (bf16w) {
        const short* h16 = (const short*)hraw;
#pragma unroll
        for (int kc = 0; kc < 4; ++kc) {
            ahi[kc] = *(const short8*)(h16 + (size_t)(i0 + lo) * NF + kc * 32 + g * 8);
            alo[kc] = (short8){0, 0, 0, 0, 0, 0, 0, 0};
        }
    } else {
        const float* hf = (const float*)hraw;
#pragma unroll
        for (int kc = 0; kc < 4; ++kc) {
            const float* p = hf + (size_t)(i0 + lo) * NF + kc * 32 + g * 8;
            float4v x0 = *(const float4v*)(p);
            float4v x1 = *(const float4v*)(p + 4);
            short8 h8, l8;
#pragma unroll
            for (int q = 0; q < 4; ++q) {
                unsigned short u0 = f2bf(x0[q]);
                h8[q] = (short)u0;
                l8[q] = (short)f2bf(x0[q] - bf2f(u0));
                unsigned short u1 = f2bf(x1[q]);
                h8[q + 4] = (short)u1;
                l8[q + 4] = (short)f2bf(x1[q] - bf2f(u1));
            }
            ahi[kc] = h8;
            alo[kc] = l8;
        }
    }

    f32x4 acc[8];
#pragma unroll
    for (int t = 0; t < 8; ++t) acc[t] = (f32x4){0.f, 0.f, 0.f, 0.f};

#pragma unroll
    for (int t = 0; t < 8; ++t) {
#pragma unroll
        for (int kc = 0; kc < 4; ++kc) {
            const size_t boff = (size_t)(lo + 16 * t) * NF + kc * 32 + g * 8;
            short8 bhi = *(const short8*)(WThi + boff);
            short8 blo = *(const short8*)(WTlo + boff);
            acc[t] = __builtin_amdgcn_mfma_f32_16x16x32_bf16(ahi[kc], bhi, acc[t], 0, 0, 0);
            acc[t] = __builtin_amdgcn_mfma_f32_16x16x32_bf16(ahi[kc], blo, acc[t], 0, 0, 0);
            acc[t] = __builtin_amdgcn_mfma_f32_16x16x32_bf16(alo[kc], bhi, acc[t], 0, 0, 0);
        }
    }

    const int b = i0 >> 11;
    const int n0 = i0 & 2047;
    short* wt = WhT + (size_t)b * NF * NN;
#pragma unroll
    for (int t = 0; t < 8; ++t) {
        ushort4v u;
#pragma unroll
        for (int r = 0; r < 4; ++r) u[r] = f2bf(acc[t][r]);
        *(ushort4v*)(wt + (size_t)(lo + 16 * t) * NN + n0 + g * 4) = u;
    }

    float a1f[8], a2f[8];
#pragma unroll
    for (int t = 0; t < 8; ++t) {
        a1f[t] = a1s[lo + 16 * t];
        a2f[t] = a2s[lo + 16 * t];
    }
#pragma unroll
    for (int r = 0; r < 4; ++r) {
        float d1 = 0.f, d2 = 0.f;
#pragma unroll
        for (int t = 0; t < 8; ++t) {
            float w = acc[t][r];
            d1 += w * a1f[t];
            d2 += w * a2f[t];
        }
#pragma unroll
        for (int off = 1; off < 16; off <<= 1) {
            d1 += __shfl_xor(d1, off);
            d2 += __shfl_xor(d2, off);
        }
        if (lo == 0) {
            s1[i0 + g * 4 + r] = d1;
            s2[i0 + g * 4 + r] = d2;
        }
    }
}

// ---------------- k_s2max: per-batch max of s2 ------------------------------
__global__ __launch_bounds__(256) void k_s2max(const float* __restrict__ s2,
                                               float* __restrict__ s2m) {
    int b = blockIdx.x;
    float m = -1e30f;
    for (int i = threadIdx.x; i < NN; i += 256) m = fmaxf(m, s2[b * NN + i]);
#pragma unroll
    for (int off = 1; off < 64; off <<= 1) m = fmaxf(m, __shfl_xor(m, off));
    __shared__ float sm[4];
    if ((threadIdx.x & 63) == 0) sm[threadIdx.x >> 6] = m;
    __syncthreads();
    if (threadIdx.x == 0)
        s2m[b] = fmaxf(fmaxf(sm[0], sm[1]), fmaxf(sm[2], sm[3]));
}

// ---------------- k_attn3: LDS-staged fused masked softmax + PV -------------
// block = 256 thr = 4 waves = 4 row-groups (64 rows), one j-range (NN/JS).
// Per 64-j tile: stage WhT[128][64] in LDS (XOR-swizzled, double-buffered);
// WhT + pk + s2 all prefetched one tile ahead.
template <int FINAL, int JS>
__global__ __launch_bounds__(256, 4) void k_attn3(const unsigned long long* __restrict__ pk,
                                                  const float* __restrict__ s1,
                                                  const float* __restrict__ s2,
                                                  const float* __restrict__ s2m,
                                                  const short* __restrict__ WhT,
                                                  const int* __restrict__ flag,
                                                  void* __restrict__ out,
                                                  float* __restrict__ pO,
                                                  float* __restrict__ pL) {
    const int tid = threadIdx.x;
    const int lane = tid & 63, wid = tid >> 6;
    const int lo = lane & 15, g = lane >> 4;
    const int gid = blockIdx.x;
    const int js = (JS > 1) ? (gid / (NB * 32)) : 0;   // js-major grid
    const int rem = gid % (NB * 32);
    const int blk = rem & 31;                  // 64-row chunk within batch
    const int b = rem >> 5;
    const int rowbase = blk * 64 + wid * 16;   // wave's 16-row group
    const int row = rowbase + lo;
    const int jbeg = js * (NN / JS);
    const int NT = (NN / JS) / 64;

    __shared__ short lds[2][128 * 64];

    const float s1v = s1[b * NN + row];
    const float tm = s1v + s2m[b];
    const float M = fmaxf(tm, 0.2f * tm);
    const unsigned long long* pkr = pk + (size_t)(b * NN + row) * PKW + (jbeg >> 6);
    const float* s2p = s2 + b * NN + jbeg;
    const short* vb = WhT + (size_t)b * NF * NN;

    // staging role: thread -> (feature, 64B half of the 128B j-row)
    const int sf = tid >> 1;
    const int sh = tid & 1;
    const short* sbase = vb + (size_t)sf * NN + jbeg + sh * 32;
    char* ldsc0 = (char*)&lds[0][0];
    char* ldsc1 = (char*)&lds[1][0];
    const unsigned swz = (unsigned)((sf & 7) << 4);
    const unsigned wb0 = (unsigned)(sf * 128 + sh * 64);
    const unsigned rsw = (unsigned)((lo & 7) << 4);

    f32x4 acc[8];
#pragma unroll
    for (int t = 0; t < 8; ++t) acc[t] = (f32x4){0.f, 0.f, 0.f, 0.f};
    float lsum = 0.f;

    // prologue: stage tile 0 + prefetch tile-0 z/pk
    {
        short8 s0 = *(const short8*)(sbase);
        short8 s1r = *(const short8*)(sbase + 8);
        short8 s2r = *(const short8*)(sbase + 16);
        short8 s3r = *(const short8*)(sbase + 24);
        *(short8*)(ldsc0 + ((wb0 + 0) ^ swz)) = s0;
        *(short8*)(ldsc0 + ((wb0 + 16) ^ swz)) = s1r;
        *(short8*)(ldsc0 + ((wb0 + 32) ^ swz)) = s2r;
        *(short8*)(ldsc0 + ((wb0 + 48) ^ swz)) = s3r;
    }
    unsigned long long mcur = pkr[0];
    float4v zc0 = *(const float4v*)(s2p + g * 8);
    float4v zc1 = *(const float4v*)(s2p + g * 8 + 4);
    float4v zc2 = *(const float4v*)(s2p + g * 8 + 32);
    float4v zc3 = *(const float4v*)(s2p + g * 8 + 36);
    __syncthreads();

    int cur = 0;
    for (int t = 0; t < NT; ++t) {
        // ---- issue next tile's loads early (hide under compute) ----
        short8 sn0, sn1, sn2, sn3;
        unsigned long long mnext = 0;
        float4v zn0, zn1, zn2, zn3;
        const bool more = (t + 1 < NT);
        if (more) {
            const short* sp = sbase + (t + 1) * 64;
            sn0 = *(const short8*)(sp);
            sn1 = *(const short8*)(sp + 8);
            sn2 = *(const short8*)(sp + 16);
            sn3 = *(const short8*)(sp + 24);
            mnext = pkr[t + 1];
            const float* zp = s2p + (t + 1) * 64 + g * 8;
            zn0 = *(const float4v*)(zp);
            zn1 = *(const float4v*)(zp + 4);
            zn2 = *(const float4v*)(zp + 32);
            zn3 = *(const float4v*)(zp + 36);
        }
        const char* cb = cur ? ldsc1 : ldsc0;

        // ---- P for this wave's 16 rows x 64 j ----
        const unsigned bits0 = (unsigned)(mcur >> (g * 8)) & 0xFFu;
        const unsigned bits1 = (unsigned)(mcur >> (32 + g * 8)) & 0xFFu;
        short8 pa0, pa1;
#pragma unroll
        for (int q = 0; q < 4; ++q) {
            float t0 = s1v + zc0[q];
            float e0 = fmaxf(t0, 0.2f * t0);
            float p0 = ((bits0 >> q) & 1u) ? exp2f(e0 - M) : 0.f;
            float t1 = s1v + zc1[q];
            float e1 = fmaxf(t1, 0.2f * t1);
            float p1 = ((bits0 >> (q + 4)) & 1u) ? exp2f(e1 - M) : 0.f;
            float t2 = s1v + zc2[q];
            float e2 = fmaxf(t2, 0.2f * t2);
            float p2 = ((bits1 >> q) & 1u) ? exp2f(e2 - M) : 0.f;
            float t3 = s1v + zc3[q];
            float e3 = fmaxf(t3, 0.2f * t3);
            float p3 = ((bits1 >> (q + 4)) & 1u) ? exp2f(e3 - M) : 0.f;
            pa0[q] = (short)f2bf(p0); pa0[q + 4] = (short)f2bf(p1);
            pa1[q] = (short)f2bf(p2); pa1[q + 4] = (short)f2bf(p3);
            lsum += p0 + p1 + p2 + p3;
        }

        // ---- 16 MFMAs, B-frags from swizzled LDS ----
#pragma unroll
        for (int t8 = 0; t8 < 8; ++t8) {
            const unsigned rb0 = ((unsigned)((lo + 16 * t8) * 128 + g * 16)) ^ rsw;
            const unsigned rb1 = ((unsigned)((lo + 16 * t8) * 128 + 64 + g * 16)) ^ rsw;
            short8 v0 = *(const short8*)(cb + rb0);
            short8 v1 = *(const short8*)(cb + rb1);
            acc[t8] = __builtin_amdgcn_mfma_f32_16x16x32_bf16(pa0, v0, acc[t8], 0, 0, 0);
            acc[t8] = __builtin_amdgcn_mfma_f32_16x16x32_bf16(pa1, v1, acc[t8], 0, 0, 0);
        }

        // ---- write staged regs into the other buffer ----
        if (more) {
            char* wb = cur ? ldsc0 : ldsc1;
            *(short8*)(wb + ((wb0 + 0) ^ swz)) = sn0;
            *(short8*)(wb + ((wb0 + 16) ^ swz)) = sn1;
            *(short8*)(wb + ((wb0 + 32) ^ swz)) = sn2;
            *(short8*)(wb + ((wb0 + 48) ^ swz)) = sn3;
            mcur = mnext;
            zc0 = zn0; zc1 = zn1; zc2 = zn2; zc3 = zn3;
        }
        __syncthreads();
        cur ^= 1;
    }

    // row-sum for row `lo` across the 4 k-slices
    lsum += __shfl_xor(lsum, 16);
    lsum += __shfl_xor(lsum, 32);

    if (FINAL) {
        const int bf16w = *flag;
        float inv[4];
#pragma unroll
        for (int r = 0; r < 4; ++r) inv[r] = 1.0f / __shfl(lsum, g * 4 + r);
#pragma unroll
        for (int t8 = 0; t8 < 8; ++t8) {
#pragma unroll
            for (int r = 0; r < 4; ++r) {
                float x = acc[t8][r] * inv[r];
                float y = (x > 0.f) ? x : (exp2f(x * LOG2E) - 1.0f);
                size_t oi = ((size_t)b * NN + rowbase + g * 4 + r) * NF + lo + 16 * t8;
                if (bf16w) ((__hip_bfloat16*)out)[oi] = __float2bfloat16(y);
                else ((float*)out)[oi] = y;
            }
        }
    } else {
        const int grp = b * 128 + blk * 4 + wid;       // 16-row group id
        float* po = pO + (size_t)(grp * JS + js) * (16 * NF);
#pragma unroll
        for (int t8 = 0; t8 < 8; ++t8)
#pragma unroll
            for (int r = 0; r < 4; ++r)
                po[(g * 4 + r) * NF + lo + 16 * t8] = acc[t8][r];
        if (g == 0) pL[(grp * JS + js) * 16 + lo] = lsum;
    }
}

// ---------------- k_combine: merge j-split partials, ELU, store -------------
__global__ __launch_bounds__(256) void k_combine(const float* __restrict__ pO,
                                                 const float* __restrict__ pL,
                                                 const int* __restrict__ flag,
                                                 void* __restrict__ out,
                                                 int jsplit) {
    int idx = blockIdx.x * 256 + threadIdx.x;   // 0 .. B*N*F-1
    if (idx >= NB * NN * NF) return;
    const int bf16w = *flag;
    int col = idx & 127;
    int rowg = idx >> 7;
    int r = rowg & 15;
    int grp = rowg >> 4;          // b*128 + 16-row group
    float o = 0.f, l = 0.f;
    for (int js = 0; js < jsplit; ++js) {
        int task = grp * jsplit + js;
        o += pO[(size_t)task * (16 * NF) + r * NF + col];
        l += pL[task * 16 + r];
    }
    float x = o / l;
    float y = (x > 0.f) ? x : (exp2f(x * LOG2E) - 1.0f);
    if (bf16w) ((__hip_bfloat16*)out)[idx] = __float2bfloat16(y);
    else ((float*)out)[idx] = y;
}

extern "C" void kernel_launch(void* const* d_in, const int* in_sizes, int n_in,
                              void* d_out, int out_size, void* d_ws, size_t ws_size,
                              hipStream_t stream) {
    const void* h = d_in[0];                    // f32 or bf16 [8][2048][128]
    const int* adj = (const int*)d_in[1];       // int32 [8][2048][2048]
    const void* W = d_in[2];                    // f32 or bf16 [128][128]
    const void* a = d_in[3];                    // f32 or bf16 [256]

    char* ws = (char*)d_ws;
    auto align256 = [](size_t x) { return (x + 255) & ~(size_t)255; };
    size_t off = 0;
    int* flag = (int*)(ws + off);     off = align256(off + 256);
    short* WThi = (short*)(ws + off); off = align256(off + (size_t)128 * 128 * 2);
    short* WTlo = (short*)(ws + off); off = align256(off + (size_t)128 * 128 * 2);
    float* a1s = (float*)(ws + off);  off = align256(off + 128 * 4);
    float* a2s = (float*)(ws + off);  off = align256(off + 128 * 4);
    short* WhT = (short*)(ws + off);  off = align256(off + (size_t)NB * NF * NN * 2);
    float* s1 = (float*)(ws + off);   off = align256(off + (size_t)NB * NN * 4);
    float* s2 = (float*)(ws + off);   off = align256(off + (size_t)NB * NN * 4);
    float* s2m = (float*)(ws + off);  off = align256(off + (size_t)NB * 4);
    unsigned long long* pk = (unsigned long long*)(ws + off);
    off = align256(off + (size_t)PKWORDS * 8);

    const int ngrp = NB * 128;                   // 16-row groups
    auto need = [&](int js) {
        return off + (size_t)ngrp * js * 16 * NF * 4 + 512 + (size_t)ngrp * js * 16 * 4;
    };
    int jsplit = (ws_size >= need(4)) ? 4 : ((ws_size >= need(2)) ? 2 : 1);
    float* pO = nullptr;
    float* pL = nullptr;
    if (jsplit > 1) {
        size_t pO_bytes = (size_t)ngrp * jsplit * 16 * NF * 4;
        size_t pL_bytes = (size_t)ngrp * jsplit * 16 * 4;
        pO = (float*)(ws + off); off = align256(off + pO_bytes);
        pL = (float*)(ws + off); off = align256(off + pL_bytes);
    }

    k_sniff<<<1, 64, 0, stream>>>((const unsigned short*)h, flag);
    k_pack<<<1024, 256, 0, stream>>>(adj, pk);
    k_prep<<<64, 256, 0, stream>>>(W, a, flag, WThi, WTlo, a1s, a2s);
    k_gemm<<<NB * NN / 16, 64, 0, stream>>>(h, flag, WThi, WTlo, a1s, a2s, s1, s2, WhT);
    k_s2max<<<NB, 256, 0, stream>>>(s2, s2m);
    if (jsplit == 4) {
        k_attn3<0, 4><<<NB * 32 * 4, 256, 0, stream>>>(pk, s1, s2, s2m, WhT, flag,
                                                       d_out, pO, pL);
    } else if (jsplit == 2) {
        k_attn3<0, 2><<<NB * 32 * 2, 256, 0, stream>>>(pk, s1, s2, s2m, WhT, flag,
                                                       d_out, pO, pL);
    } else {
        k_attn3<1, 1><<<NB * 32, 256, 0, stream>>>(pk, s1, s2, s2m, WhT, flag,
                                                   d_out, nullptr, nullptr);
    }
    if (jsplit > 1) {
        int nout = NB * NN * NF;
        k_combine<<<(nout + 255) / 256, 256, 0, stream>>>(pO, pL, flag, d_out, jsplit);
    }
}